// Round 11
// baseline (301.002 us; speedup 1.0000x reference)
//
#include <hip/hip_runtime.h>
#include <math.h>

#define N_NODES 100000
#define N_EDGES 1600000
#define IN_CH 256
#define HID_CH 128
#define OUT_CH 64
#define NTILES ((N_NODES + 63) / 64)     // 1563 m-tiles of 64 rows
#define NB 1024                          // buckets: node >> 7
#define NPART 256                        // partition blocks
#define EPB (N_EDGES / NPART)            // 6250 edges per partition block
#define NB_USED ((N_NODES + 127) / 128)  // 782 used buckets / 128-node gather blocks
#define LCAP 4096                        // LDS index cap per gather block

typedef short s16x8 __attribute__((ext_vector_type(8)));
typedef unsigned short u16x8 __attribute__((ext_vector_type(8)));
typedef float f32x4 __attribute__((ext_vector_type(4)));

__device__ __forceinline__ float bf2f(unsigned short u) {
    union { unsigned int i; float f; } v;
    v.i = ((unsigned int)u) << 16;
    return v.f;
}
__device__ __forceinline__ unsigned short f2bf(float f) {
    union { float f; unsigned int i; } v;
    v.f = f;
    unsigned int u = v.i;
    return (unsigned short)((u + 0x7FFFu + ((u >> 16) & 1u)) >> 16);  // RNE
}

// ---------------- CSR build: LDS-histogram radix partition (no global atomics) ----------------

__global__ __launch_bounds__(256) void k_hist(const int* __restrict__ dst,
                                              int* __restrict__ ghist) {
    __shared__ int h[NB];
    int b = blockIdx.x, t = threadIdx.x;
    for (int k = t; k < NB; k += 256) h[k] = 0;
    __syncthreads();
    int e0 = b * EPB;
    for (int e = e0 + t; e < e0 + EPB; e += 256)
        atomicAdd(&h[dst[e] >> 7], 1);
    __syncthreads();
    for (int k = t; k < NB; k += 256) ghist[k * NPART + b] = h[k];
}

__global__ __launch_bounds__(256) void k_scan_cols(const int* __restrict__ ghist,
                                                   int* __restrict__ goff,
                                                   int* __restrict__ btot) {
    __shared__ int tmp[NPART];
    int k = blockIdx.x, t = threadIdx.x;
    int v = ghist[k * NPART + t];
    tmp[t] = v;
    __syncthreads();
    for (int off = 1; off < NPART; off <<= 1) {
        int u = (t >= off) ? tmp[t - off] : 0;
        __syncthreads();
        tmp[t] += u;
        __syncthreads();
    }
    goff[k * NPART + t] = tmp[t] - v;
    if (t == NPART - 1) btot[k] = tmp[t];
}

__global__ __launch_bounds__(1024) void k_scan_base(const int* __restrict__ btot,
                                                    int* __restrict__ bbase) {
    __shared__ int tmp[NB];
    int t = threadIdx.x;
    int v = btot[t];
    tmp[t] = v;
    __syncthreads();
    for (int off = 1; off < NB; off <<= 1) {
        int u = (t >= off) ? tmp[t - off] : 0;
        __syncthreads();
        tmp[t] += u;
        __syncthreads();
    }
    bbase[t] = tmp[t] - v;
    if (t == NB - 1) bbase[NB] = tmp[t];
}

__global__ __launch_bounds__(256) void k_partition(const int* __restrict__ src,
                                                   const int* __restrict__ dst,
                                                   const int* __restrict__ goff,
                                                   const int* __restrict__ bbase,
                                                   int2* __restrict__ bsorted) {
    __shared__ int cur[NB];
    int b = blockIdx.x, t = threadIdx.x;
    for (int k = t; k < NB; k += 256) cur[k] = bbase[k] + goff[k * NPART + b];
    __syncthreads();
    int e0 = b * EPB;
    for (int e = e0 + t; e < e0 + EPB; e += 256) {
        int s = src[e], d = dst[e];
        int pos = atomicAdd(&cur[d >> 7], 1);
        bsorted[pos] = make_int2(s, d);
    }
}

__global__ __launch_bounds__(256) void k_bucket_csr(const int2* __restrict__ bsorted,
                                                    const int* __restrict__ bbase,
                                                    int* __restrict__ rowoff,
                                                    float* __restrict__ dinv,
                                                    int* __restrict__ csr_src) {
    __shared__ int cnt[128];
    __shared__ int tmp[256];
    __shared__ int cur[128];
    int b = blockIdx.x, t = threadIdx.x;
    int ebeg = bbase[b], eend = bbase[b + 1];
    if (t < 128) cnt[t] = 0;
    __syncthreads();
    for (int e = ebeg + t; e < eend; e += 256)
        atomicAdd(&cnt[bsorted[e].y & 127], 1);
    __syncthreads();
    int v = (t < 128) ? cnt[t] : 0;
    tmp[t] = v;
    __syncthreads();
    for (int off = 1; off < 256; off <<= 1) {
        int u = (t >= off) ? tmp[t - off] : 0;
        __syncthreads();
        tmp[t] += u;
        __syncthreads();
    }
    if (t < 128) {
        int base = ebeg + tmp[t] - v;
        cur[t] = base;
        int node = b * 128 + t;
        if (node < N_NODES) {
            rowoff[node] = base;
            dinv[node] = rsqrtf((float)v + 1.0f);
        }
    }
    __syncthreads();
    for (int e = ebeg + t; e < eend; e += 256) {
        int2 ed = bsorted[e];
        int pos = atomicAdd(&cur[ed.y & 127], 1);
        csr_src[pos] = ed.x;
    }
}

// ---------------- streaming cast: xb = bf16(x), fully contiguous ----------------
__global__ __launch_bounds__(256) void k_cast(const float* __restrict__ x,
                                              unsigned short* __restrict__ xb) {
    const int total = N_NODES * IN_CH / 8;
    int stride = gridDim.x * 256;
    for (int i = blockIdx.x * 256 + threadIdx.x; i < total; i += stride) {
        f32x4 a = *reinterpret_cast<const f32x4*>(x + (size_t)i * 8);
        f32x4 b = *reinterpret_cast<const f32x4*>(x + (size_t)i * 8 + 4);
        u16x8 o;
        o[0] = f2bf(a[0]); o[1] = f2bf(a[1]); o[2] = f2bf(a[2]); o[3] = f2bf(a[3]);
        o[4] = f2bf(b[0]); o[5] = f2bf(b[1]); o[6] = f2bf(b[2]); o[7] = f2bf(b[3]);
        *reinterpret_cast<u16x8*>(xb + (size_t)i * 8) = o;
    }
}

// ---------------- W -> fragment-linear bf16 layout ----------------
__global__ void k_wt1(const float* __restrict__ W1, unsigned short* __restrict__ Wf1) {
    int u = blockIdx.x * 256 + threadIdx.x;
    int f = u >> 6, lane = u & 63;
    int kk = f >> 3, nt = f & 7;
    int l15 = lane & 15, lhi = lane >> 4;
    int n = nt * 16 + l15;
    int kbase = kk * 32 + lhi * 8;
    #pragma unroll
    for (int j = 0; j < 8; ++j)
        Wf1[(size_t)u * 8 + j] = f2bf(W1[(size_t)(kbase + j) * HID_CH + n]);
}

__global__ void k_wt2(const float* __restrict__ W2, unsigned short* __restrict__ Wf2) {
    int u = blockIdx.x * 256 + threadIdx.x;
    int f = u >> 6, lane = u & 63;
    int kk = f >> 2, nt = f & 3;
    int l15 = lane & 15, lhi = lane >> 4;
    int n = nt * 16 + l15;
    int kbase = kk * 32 + lhi * 8;
    #pragma unroll
    for (int j = 0; j < 8; ++j)
        Wf2[(size_t)u * 8 + j] = f2bf(W2[(size_t)(kbase + j) * OUT_CH + n]);
}

// ---------------- GEMM1: channel-SLICED output hs1s[nt][row][16] ----------------
__global__ __launch_bounds__(256, 4) void k_gemm1(const unsigned short* __restrict__ xb,
                                                  const unsigned short* __restrict__ Wf1,
                                                  const float* __restrict__ dinv,
                                                  unsigned short* __restrict__ hs1s) {
    int tid = threadIdx.x;
    int w = tid >> 6;
    int lane = tid & 63;
    int l15 = lane & 15;
    int lhi = lane >> 4;
    int m0 = blockIdx.x * 64;

    int arow = m0 + w * 16 + l15;
    int arowc = (arow < N_NODES) ? arow : (N_NODES - 1);
    const s16x8* ap = reinterpret_cast<const s16x8*>(xb + (size_t)arowc * IN_CH) + lhi;

    s16x8 af[8];
    #pragma unroll
    for (int kk = 0; kk < 8; ++kk) af[kk] = ap[kk * 4];

    const s16x8* wp = reinterpret_cast<const s16x8*>(Wf1) + lane;

    f32x4 acc[8] = {};
    #pragma unroll
    for (int kk = 0; kk < 8; ++kk) {
        #pragma unroll
        for (int nt = 0; nt < 8; ++nt) {
            s16x8 bf = wp[(kk * 8 + nt) * 64];
            acc[nt] = __builtin_amdgcn_mfma_f32_16x16x32_bf16(af[kk], bf, acc[nt], 0, 0, 0);
        }
    }

    float dv[4];
    int rb = m0 + w * 16 + lhi * 4;
    #pragma unroll
    for (int r = 0; r < 4; ++r) dv[r] = (rb + r < N_NODES) ? dinv[rb + r] : 0.0f;
    #pragma unroll
    for (int nt = 0; nt < 8; ++nt) {
        #pragma unroll
        for (int r = 0; r < 4; ++r) {
            int row = rb + r;
            if (row < N_NODES)
                hs1s[((size_t)nt * N_NODES + row) * 16 + l15] = f2bf(dv[r] * acc[nt][r]);
        }
    }
}

// ---------------- GEMM2: channel-SLICED output hs2s[nt][row][16] ----------------
__global__ __launch_bounds__(256, 4) void k_gemm2(const unsigned short* __restrict__ h1r,
                                                  const unsigned short* __restrict__ Wf2,
                                                  const float* __restrict__ dinv,
                                                  unsigned short* __restrict__ hs2s) {
    int tid = threadIdx.x;
    int w = tid >> 6;
    int lane = tid & 63;
    int l15 = lane & 15;
    int lhi = lane >> 4;
    int m0 = blockIdx.x * 64;

    int arow = m0 + w * 16 + l15;
    int arowc = (arow < N_NODES) ? arow : (N_NODES - 1);
    const s16x8* ap = reinterpret_cast<const s16x8*>(h1r + (size_t)arowc * HID_CH) + lhi;

    s16x8 af[4];
    #pragma unroll
    for (int kk = 0; kk < 4; ++kk) af[kk] = ap[kk * 4];

    const s16x8* wp = reinterpret_cast<const s16x8*>(Wf2) + lane;

    f32x4 acc[4] = {};
    #pragma unroll
    for (int kk = 0; kk < 4; ++kk) {
        #pragma unroll
        for (int nt = 0; nt < 4; ++nt) {
            s16x8 bf = wp[(kk * 4 + nt) * 64];
            acc[nt] = __builtin_amdgcn_mfma_f32_16x16x32_bf16(af[kk], bf, acc[nt], 0, 0, 0);
        }
    }

    float dv[4];
    int rb = m0 + w * 16 + lhi * 4;
    #pragma unroll
    for (int r = 0; r < 4; ++r) dv[r] = (rb + r < N_NODES) ? dinv[rb + r] : 0.0f;
    #pragma unroll
    for (int nt = 0; nt < 4; ++nt) {
        #pragma unroll
        for (int r = 0; r < 4; ++r) {
            int row = rb + r;
            if (row < N_NODES)
                hs2s[((size_t)nt * N_NODES + row) * 16 + l15] = f2bf(dv[r] * acc[nt][r]);
        }
    }
}

// ---------------- channel-sliced gather aggregation ----------------
// Grid (NB_USED, C/16). Plane p (16ch, 3.2MB) is L2-resident while its blocks run.
// Block: 128 nodes, edge indices staged in LDS (contiguous CSR range), 2 lanes/node.
// out[node][p*16 + q*8 + j] = [relu]( dinv*(self + sum nbr) + b )   (standard layout)
template <int C, bool RELU>
__global__ __launch_bounds__(256) void k_gather_sl(const int* __restrict__ rowoff,
                                                   const int* __restrict__ csr_src,
                                                   const unsigned short* __restrict__ hsS,
                                                   const float* __restrict__ dinv,
                                                   const float* __restrict__ b,
                                                   unsigned short* __restrict__ outp) {
    __shared__ int lidx[LCAP];
    int bx = blockIdx.x, p = blockIdx.y, t = threadIdx.x;
    int n0 = bx * 128;
    int ebeg = rowoff[n0];
    int eend = (n0 + 128 < N_NODES) ? rowoff[n0 + 128] : N_EDGES;
    int cnt = eend - ebeg;

    for (int i = t; i < cnt && i < LCAP; i += 256) lidx[i] = csr_src[ebeg + i];
    __syncthreads();

    int node = n0 + (t >> 1);
    int q = t & 1;
    if (node >= N_NODES) return;

    const unsigned short* P = hsS + (size_t)p * N_NODES * 16;
    int lbeg = rowoff[node] - ebeg;
    int lend = ((node + 1 < N_NODES) ? rowoff[node + 1] : N_EDGES) - ebeg;

    float acc[8];
    {
        u16x8 sv = *reinterpret_cast<const u16x8*>(P + ((size_t)node << 4) + (q << 3));
        #pragma unroll
        for (int j = 0; j < 8; ++j) acc[j] = bf2f(sv[j]);
    }

    if (cnt <= LCAP) {
        int i = lbeg;
        for (; i + 3 < lend; i += 4) {
            int s0 = lidx[i], s1 = lidx[i + 1], s2 = lidx[i + 2], s3 = lidx[i + 3];
            u16x8 v0 = *reinterpret_cast<const u16x8*>(P + ((size_t)s0 << 4) + (q << 3));
            u16x8 v1 = *reinterpret_cast<const u16x8*>(P + ((size_t)s1 << 4) + (q << 3));
            u16x8 v2 = *reinterpret_cast<const u16x8*>(P + ((size_t)s2 << 4) + (q << 3));
            u16x8 v3 = *reinterpret_cast<const u16x8*>(P + ((size_t)s3 << 4) + (q << 3));
            #pragma unroll
            for (int j = 0; j < 8; ++j)
                acc[j] += (bf2f(v0[j]) + bf2f(v1[j])) + (bf2f(v2[j]) + bf2f(v3[j]));
        }
        for (; i < lend; ++i) {
            int s0 = lidx[i];
            u16x8 v0 = *reinterpret_cast<const u16x8*>(P + ((size_t)s0 << 4) + (q << 3));
            #pragma unroll
            for (int j = 0; j < 8; ++j) acc[j] += bf2f(v0[j]);
        }
    } else {  // fallback (distribution-independent correctness)
        for (int i = lbeg; i < lend; ++i) {
            int s0 = csr_src[ebeg + i];
            u16x8 v0 = *reinterpret_cast<const u16x8*>(P + ((size_t)s0 << 4) + (q << 3));
            #pragma unroll
            for (int j = 0; j < 8; ++j) acc[j] += bf2f(v0[j]);
        }
    }

    float w = dinv[node];
    float4 b0 = *reinterpret_cast<const float4*>(&b[p * 16 + q * 8]);
    float4 b1 = *reinterpret_cast<const float4*>(&b[p * 16 + q * 8 + 4]);
    float bb[8] = {b0.x, b0.y, b0.z, b0.w, b1.x, b1.y, b1.z, b1.w};
    u16x8 o;
    #pragma unroll
    for (int j = 0; j < 8; ++j) {
        float v = w * acc[j] + bb[j];
        if (RELU) v = fmaxf(v, 0.0f);
        o[j] = f2bf(v);
    }
    *reinterpret_cast<u16x8*>(outp + (size_t)node * C + p * 16 + (q << 3)) = o;
}

// ---------------- decoder ----------------

__global__ __launch_bounds__(256) void k_decode(const int* __restrict__ esrc,
                                                const int* __restrict__ edst,
                                                const unsigned short* __restrict__ z,
                                                float* __restrict__ out) {
    int tid = threadIdx.x;
    int e = blockIdx.x * 32 + tid / 8;
    int q = tid % 8;
    if (e >= N_EDGES) return;
    int s = esrc[e], d = edst[e];
    u16x8 a = *reinterpret_cast<const u16x8*>(&z[(size_t)s * OUT_CH + q * 8]);
    u16x8 b = *reinterpret_cast<const u16x8*>(&z[(size_t)d * OUT_CH + q * 8]);
    float dot = 0.0f;
    #pragma unroll
    for (int j = 0; j < 8; ++j) dot += bf2f(a[j]) * bf2f(b[j]);
    dot += __shfl_xor(dot, 1);
    dot += __shfl_xor(dot, 2);
    dot += __shfl_xor(dot, 4);
    if (q == 0) out[e] = 1.0f / (1.0f + expf(-dot));
}

// ---------------- launch ----------------

extern "C" void kernel_launch(void* const* d_in, const int* in_sizes, int n_in,
                              void* d_out, int out_size, void* d_ws, size_t ws_size,
                              hipStream_t stream) {
    const float* x  = (const float*)d_in[0];
    const int*   ei = (const int*)d_in[1];
    const float* W1 = (const float*)d_in[2];
    const float* b1 = (const float*)d_in[3];
    const float* W2 = (const float*)d_in[4];
    const float* b2 = (const float*)d_in[5];
    float* out = (float*)d_out;

    const int* src = ei;
    const int* dst = ei + N_EDGES;

    // workspace layout (byte offsets); overlays exploit liveness:
    //   bsorted dead after k_bucket_csr -> xb overlays it
    //   xb dead after k_gemm1 -> h1r/z overlay it
    //   hs1s dead after gather1 -> hs2s overlays it
    char* ws = (char*)d_ws;
    int*   ghist   = (int*)(ws + 0x000000);       // 1 MB
    int*   goff    = (int*)(ws + 0x100000);       // 1 MB
    int*   btot    = (int*)(ws + 0x200000);       // 4 KB
    int*   bbase   = (int*)(ws + 0x202000);       // 4.1 KB
    int*   rowoff  = (int*)(ws + 0x210000);       // 400 KB
    float* dinv    = (float*)(ws + 0x290000);     // 400 KB
    unsigned short* Wf1 = (unsigned short*)(ws + 0x310000);   // 64 KB frag-linear
    unsigned short* Wf2 = (unsigned short*)(ws + 0x320000);   // 16 KB frag-linear
    int*   csr_src = (int*)(ws + 0x400000);       // 6.4 MB
    int2*  bsorted = (int2*)(ws + 0xB00000);      // 12.8 MB (dead after CSR build)
    unsigned short* xb   = (unsigned short*)(ws + 0xB00000);   // 51.2 MB
    unsigned short* hs1s = (unsigned short*)(ws + 0x3C00000);  // 25.6 MB (8 planes)
    unsigned short* h1r  = (unsigned short*)(ws + 0xB00000);   // 25.6 MB (over dead xb)
    unsigned short* hs2s = (unsigned short*)(ws + 0x3C00000);  // 12.8 MB (over dead hs1s)
    unsigned short* z    = (unsigned short*)(ws + 0x2800000);  // 12.8 MB (over dead xb tail)

    // --- CSR build (no global atomics) ---
    k_hist<<<NPART, 256, 0, stream>>>(dst, ghist);
    k_scan_cols<<<NB, 256, 0, stream>>>(ghist, goff, btot);
    k_scan_base<<<1, NB, 0, stream>>>(btot, bbase);
    k_partition<<<NPART, 256, 0, stream>>>(src, dst, goff, bbase, bsorted);
    k_bucket_csr<<<NB_USED, 256, 0, stream>>>(bsorted, bbase, rowoff, dinv, csr_src);

    // --- x cast + weight fragment layout ---
    k_cast<<<2048, 256, 0, stream>>>(x, xb);
    k_wt1<<<16, 256, 0, stream>>>(W1, Wf1);
    k_wt2<<<4, 256, 0, stream>>>(W2, Wf2);

    // --- layer 1 ---
    k_gemm1<<<NTILES, 256, 0, stream>>>(xb, Wf1, dinv, hs1s);
    k_gather_sl<HID_CH, true><<<dim3(NB_USED, HID_CH / 16), 256, 0, stream>>>(
        rowoff, csr_src, hs1s, dinv, b1, h1r);

    // --- layer 2 ---
    k_gemm2<<<NTILES, 256, 0, stream>>>(h1r, Wf2, dinv, hs2s);
    k_gather_sl<OUT_CH, false><<<dim3(NB_USED, OUT_CH / 16), 256, 0, stream>>>(
        rowoff, csr_src, hs2s, dinv, b2, z);

    // --- decoder ---
    k_decode<<<N_EDGES / 32, 256, 0, stream>>>(src, dst, z, out);
}

// Round 12
// 262.577 us; speedup vs baseline: 1.1463x; 1.1463x over previous
//
#include <hip/hip_runtime.h>
#include <math.h>

#define N_NODES 100000
#define N_EDGES 1600000
#define IN_CH 256
#define HID_CH 128
#define OUT_CH 64
#define NTILES ((N_NODES + 63) / 64)     // 1563 m-tiles of 64 rows
#define NB 1024                          // buckets: node >> 7
#define NPART 256                        // partition blocks
#define EPB (N_EDGES / NPART)            // 6250 edges per partition block
#define NB_USED ((N_NODES + 127) / 128)  // 782 used buckets

typedef short s16x8 __attribute__((ext_vector_type(8)));
typedef unsigned short u16x8 __attribute__((ext_vector_type(8)));
typedef float f32x4 __attribute__((ext_vector_type(4)));

__device__ __forceinline__ float bf2f(unsigned short u) {
    union { unsigned int i; float f; } v;
    v.i = ((unsigned int)u) << 16;
    return v.f;
}
__device__ __forceinline__ unsigned short f2bf(float f) {
    union { float f; unsigned int i; } v;
    v.f = f;
    unsigned int u = v.i;
    return (unsigned short)((u + 0x7FFFu + ((u >> 16) & 1u)) >> 16);  // RNE
}

// ---------------- CSR build: LDS-histogram radix partition (no global atomics) ----------------

__global__ __launch_bounds__(256) void k_hist(const int* __restrict__ dst,
                                              int* __restrict__ ghist) {
    __shared__ int h[NB];
    int b = blockIdx.x, t = threadIdx.x;
    for (int k = t; k < NB; k += 256) h[k] = 0;
    __syncthreads();
    int e0 = b * EPB;
    for (int e = e0 + t; e < e0 + EPB; e += 256)
        atomicAdd(&h[dst[e] >> 7], 1);
    __syncthreads();
    for (int k = t; k < NB; k += 256) ghist[k * NPART + b] = h[k];
}

__global__ __launch_bounds__(256) void k_scan_cols(const int* __restrict__ ghist,
                                                   int* __restrict__ goff,
                                                   int* __restrict__ btot) {
    __shared__ int tmp[NPART];
    int k = blockIdx.x, t = threadIdx.x;
    int v = ghist[k * NPART + t];
    tmp[t] = v;
    __syncthreads();
    for (int off = 1; off < NPART; off <<= 1) {
        int u = (t >= off) ? tmp[t - off] : 0;
        __syncthreads();
        tmp[t] += u;
        __syncthreads();
    }
    goff[k * NPART + t] = tmp[t] - v;
    if (t == NPART - 1) btot[k] = tmp[t];
}

__global__ __launch_bounds__(1024) void k_scan_base(const int* __restrict__ btot,
                                                    int* __restrict__ bbase) {
    __shared__ int tmp[NB];
    int t = threadIdx.x;
    int v = btot[t];
    tmp[t] = v;
    __syncthreads();
    for (int off = 1; off < NB; off <<= 1) {
        int u = (t >= off) ? tmp[t - off] : 0;
        __syncthreads();
        tmp[t] += u;
        __syncthreads();
    }
    bbase[t] = tmp[t] - v;
    if (t == NB - 1) bbase[NB] = tmp[t];
}

__global__ __launch_bounds__(256) void k_partition(const int* __restrict__ src,
                                                   const int* __restrict__ dst,
                                                   const int* __restrict__ goff,
                                                   const int* __restrict__ bbase,
                                                   int2* __restrict__ bsorted) {
    __shared__ int cur[NB];
    int b = blockIdx.x, t = threadIdx.x;
    for (int k = t; k < NB; k += 256) cur[k] = bbase[k] + goff[k * NPART + b];
    __syncthreads();
    int e0 = b * EPB;
    for (int e = e0 + t; e < e0 + EPB; e += 256) {
        int s = src[e], d = dst[e];
        int pos = atomicAdd(&cur[d >> 7], 1);
        bsorted[pos] = make_int2(s, d);
    }
}

__global__ __launch_bounds__(256) void k_bucket_csr(const int2* __restrict__ bsorted,
                                                    const int* __restrict__ bbase,
                                                    int* __restrict__ rowoff,
                                                    float* __restrict__ dinv,
                                                    int* __restrict__ csr_src) {
    __shared__ int cnt[128];
    __shared__ int tmp[256];
    __shared__ int cur[128];
    int b = blockIdx.x, t = threadIdx.x;
    int ebeg = bbase[b], eend = bbase[b + 1];
    if (t < 128) cnt[t] = 0;
    __syncthreads();
    for (int e = ebeg + t; e < eend; e += 256)
        atomicAdd(&cnt[bsorted[e].y & 127], 1);
    __syncthreads();
    int v = (t < 128) ? cnt[t] : 0;
    tmp[t] = v;
    __syncthreads();
    for (int off = 1; off < 256; off <<= 1) {
        int u = (t >= off) ? tmp[t - off] : 0;
        __syncthreads();
        tmp[t] += u;
        __syncthreads();
    }
    if (t < 128) {
        int base = ebeg + tmp[t] - v;
        cur[t] = base;
        int node = b * 128 + t;
        if (node < N_NODES) {
            rowoff[node] = base;
            dinv[node] = rsqrtf((float)v + 1.0f);
        }
    }
    __syncthreads();
    for (int e = ebeg + t; e < eend; e += 256) {
        int2 ed = bsorted[e];
        int pos = atomicAdd(&cur[ed.y & 127], 1);
        csr_src[pos] = ed.x;
    }
}

// ---------------- streaming cast: xb = bf16(x), fully contiguous ----------------
__global__ __launch_bounds__(256) void k_cast(const float* __restrict__ x,
                                              unsigned short* __restrict__ xb) {
    const int total = N_NODES * IN_CH / 8;
    int stride = gridDim.x * 256;
    for (int i = blockIdx.x * 256 + threadIdx.x; i < total; i += stride) {
        f32x4 a = *reinterpret_cast<const f32x4*>(x + (size_t)i * 8);
        f32x4 b = *reinterpret_cast<const f32x4*>(x + (size_t)i * 8 + 4);
        u16x8 o;
        o[0] = f2bf(a[0]); o[1] = f2bf(a[1]); o[2] = f2bf(a[2]); o[3] = f2bf(a[3]);
        o[4] = f2bf(b[0]); o[5] = f2bf(b[1]); o[6] = f2bf(b[2]); o[7] = f2bf(b[3]);
        *reinterpret_cast<u16x8*>(xb + (size_t)i * 8) = o;
    }
}

// ---------------- W -> fragment-linear bf16 layout ----------------
__global__ void k_wt1(const float* __restrict__ W1, unsigned short* __restrict__ Wf1) {
    int u = blockIdx.x * 256 + threadIdx.x;
    int f = u >> 6, lane = u & 63;
    int kk = f >> 3, nt = f & 7;
    int l15 = lane & 15, lhi = lane >> 4;
    int n = nt * 16 + l15;
    int kbase = kk * 32 + lhi * 8;
    #pragma unroll
    for (int j = 0; j < 8; ++j)
        Wf1[(size_t)u * 8 + j] = f2bf(W1[(size_t)(kbase + j) * HID_CH + n]);
}

__global__ void k_wt2(const float* __restrict__ W2, unsigned short* __restrict__ Wf2) {
    int u = blockIdx.x * 256 + threadIdx.x;
    int f = u >> 6, lane = u & 63;
    int kk = f >> 2, nt = f & 3;
    int l15 = lane & 15, lhi = lane >> 4;
    int n = nt * 16 + l15;
    int kbase = kk * 32 + lhi * 8;
    #pragma unroll
    for (int j = 0; j < 8; ++j)
        Wf2[(size_t)u * 8 + j] = f2bf(W2[(size_t)(kbase + j) * OUT_CH + n]);
}

// ---------------- GEMM1: hs1[m][n] = bf16( dinv[m] * sum_k xb[m][k] W1[k][n] ) ----------------
__global__ __launch_bounds__(256, 4) void k_gemm1(const unsigned short* __restrict__ xb,
                                                  const unsigned short* __restrict__ Wf1,
                                                  const float* __restrict__ dinv,
                                                  unsigned short* __restrict__ hs1) {
    int tid = threadIdx.x;
    int w = tid >> 6;
    int lane = tid & 63;
    int l15 = lane & 15;
    int lhi = lane >> 4;
    int m0 = blockIdx.x * 64;

    int arow = m0 + w * 16 + l15;
    int arowc = (arow < N_NODES) ? arow : (N_NODES - 1);
    const s16x8* ap = reinterpret_cast<const s16x8*>(xb + (size_t)arowc * IN_CH) + lhi;

    s16x8 af[8];
    #pragma unroll
    for (int kk = 0; kk < 8; ++kk) af[kk] = ap[kk * 4];

    const s16x8* wp = reinterpret_cast<const s16x8*>(Wf1) + lane;

    f32x4 acc[8] = {};
    #pragma unroll
    for (int kk = 0; kk < 8; ++kk) {
        #pragma unroll
        for (int nt = 0; nt < 8; ++nt) {
            s16x8 bf = wp[(kk * 8 + nt) * 64];
            acc[nt] = __builtin_amdgcn_mfma_f32_16x16x32_bf16(af[kk], bf, acc[nt], 0, 0, 0);
        }
    }

    float dv[4];
    int rb = m0 + w * 16 + lhi * 4;
    #pragma unroll
    for (int r = 0; r < 4; ++r) dv[r] = (rb + r < N_NODES) ? dinv[rb + r] : 0.0f;
    #pragma unroll
    for (int nt = 0; nt < 8; ++nt) {
        #pragma unroll
        for (int r = 0; r < 4; ++r) {
            int row = rb + r;
            if (row < N_NODES)
                hs1[(size_t)row * HID_CH + nt * 16 + l15] = f2bf(dv[r] * acc[nt][r]);
        }
    }
}

// ---------------- FUSED gather1 + GEMM2 ----------------
// Phase 1: 64 nodes/block, 4 lanes/node gather-aggregate hs1 rows (256B, full lines),
//          bias+ReLU, pack bf16 into 16KB LDS tile (XOR-swizzled 16B units).
// Phase 2: 4 waves MFMA tile(64x128) @ Wf2(128x64) -> hs2 (dinv-scaled), no h1r roundtrip.
__global__ __launch_bounds__(256) void k_agg_gemm2(const int* __restrict__ rowoff,
                                                   const int* __restrict__ csr_src,
                                                   const unsigned short* __restrict__ hs1,
                                                   const float* __restrict__ dinv,
                                                   const float* __restrict__ b1,
                                                   const unsigned short* __restrict__ Wf2,
                                                   unsigned short* __restrict__ hs2) {
    __shared__ unsigned short tile[64 * 128];  // 16 KB
    int t = threadIdx.x;
    int n0 = blockIdx.x * 64;
    int nl = t >> 2;          // 0..63 local node
    int q = t & 3;            // 32-ch slice
    int node = n0 + nl;
    bool valid = node < N_NODES;
    int nodec = valid ? node : (N_NODES - 1);

    int beg = 0, end = 0;
    if (valid) {
        beg = rowoff[node];
        end = (node + 1 < N_NODES) ? rowoff[node + 1] : N_EDGES;
    }

    const unsigned short* base = hs1 + q * 32;

    float acc[4][8];
    #pragma unroll
    for (int j = 0; j < 4; ++j) {
        u16x8 v = *reinterpret_cast<const u16x8*>(base + (size_t)nodec * HID_CH + j * 8);
        #pragma unroll
        for (int c = 0; c < 8; ++c) acc[j][c] = bf2f(v[c]);
    }

    int i = beg;
    for (; i + 1 < end; i += 2) {
        int s0 = csr_src[i], s1 = csr_src[i + 1];
        u16x8 v0[4], v1[4];
        #pragma unroll
        for (int j = 0; j < 4; ++j)
            v0[j] = *reinterpret_cast<const u16x8*>(base + (size_t)s0 * HID_CH + j * 8);
        #pragma unroll
        for (int j = 0; j < 4; ++j)
            v1[j] = *reinterpret_cast<const u16x8*>(base + (size_t)s1 * HID_CH + j * 8);
        #pragma unroll
        for (int j = 0; j < 4; ++j)
            #pragma unroll
            for (int c = 0; c < 8; ++c) acc[j][c] += bf2f(v0[j][c]) + bf2f(v1[j][c]);
    }
    if (i < end) {
        int s0 = csr_src[i];
        #pragma unroll
        for (int j = 0; j < 4; ++j) {
            u16x8 v0 = *reinterpret_cast<const u16x8*>(base + (size_t)s0 * HID_CH + j * 8);
            #pragma unroll
            for (int c = 0; c < 8; ++c) acc[j][c] += bf2f(v0[c]);
        }
    }

    float w = valid ? dinv[node] : 0.0f;
    #pragma unroll
    for (int j = 0; j < 4; ++j) {
        float4 ba = *reinterpret_cast<const float4*>(b1 + q * 32 + j * 8);
        float4 bb = *reinterpret_cast<const float4*>(b1 + q * 32 + j * 8 + 4);
        float bv[8] = {ba.x, ba.y, ba.z, ba.w, bb.x, bb.y, bb.z, bb.w};
        u16x8 o;
        #pragma unroll
        for (int c = 0; c < 8; ++c)
            o[c] = f2bf(fmaxf(w * acc[j][c] + bv[c], 0.0f));
        int u = (q * 4 + j) ^ (nl & 15);   // swizzled 16B unit
        *reinterpret_cast<u16x8*>(&tile[nl * 128 + u * 8]) = o;
    }
    __syncthreads();

    // ---- phase 2: MFMA ----
    int w4 = t >> 6;
    int lane = t & 63;
    int l15 = lane & 15;
    int lhi = lane >> 4;
    int R = w4 * 16 + l15;

    s16x8 af[4];
    #pragma unroll
    for (int kk = 0; kk < 4; ++kk) {
        int cu = (kk * 4 + lhi) ^ (R & 15);
        af[kk] = *reinterpret_cast<const s16x8*>(&tile[R * 128 + cu * 8]);
    }

    const s16x8* wp = reinterpret_cast<const s16x8*>(Wf2) + lane;
    f32x4 acc2[4] = {};
    #pragma unroll
    for (int kk = 0; kk < 4; ++kk) {
        #pragma unroll
        for (int nt = 0; nt < 4; ++nt) {
            s16x8 bf = wp[(kk * 4 + nt) * 64];
            acc2[nt] = __builtin_amdgcn_mfma_f32_16x16x32_bf16(af[kk], bf, acc2[nt], 0, 0, 0);
        }
    }

    float dv[4];
    int rb = n0 + w4 * 16 + lhi * 4;
    #pragma unroll
    for (int r = 0; r < 4; ++r) dv[r] = (rb + r < N_NODES) ? dinv[rb + r] : 0.0f;
    #pragma unroll
    for (int nt = 0; nt < 4; ++nt) {
        #pragma unroll
        for (int r = 0; r < 4; ++r) {
            int row = rb + r;
            if (row < N_NODES)
                hs2[(size_t)row * OUT_CH + nt * 16 + l15] = f2bf(dv[r] * acc2[nt][r]);
        }
    }
}

// ---------------- gather aggregation (bf16 rows, fp32 accum, unroll-4) ----------------
template <int C, bool RELU>
__global__ __launch_bounds__(256) void k_gather_agg(const int* __restrict__ rowoff,
                                                    const int* __restrict__ csr_src,
                                                    const unsigned short* __restrict__ hs,
                                                    const float* __restrict__ dinv,
                                                    const float* __restrict__ b,
                                                    unsigned short* __restrict__ outp) {
    constexpr int TPN = C / 8;
    constexpr int NPB = 256 / TPN;
    int t = threadIdx.x;
    int node = blockIdx.x * NPB + t / TPN;
    int q = t % TPN;
    if (node >= N_NODES) return;

    int beg = rowoff[node];
    int end = (node + 1 < N_NODES) ? rowoff[node + 1] : N_EDGES;

    float acc[8];
    {
        u16x8 sv = *reinterpret_cast<const u16x8*>(&hs[(size_t)node * C + q * 8]);
        #pragma unroll
        for (int j = 0; j < 8; ++j) acc[j] = bf2f(sv[j]);
    }

    int i = beg;
    for (; i + 3 < end; i += 4) {
        int s0 = csr_src[i], s1 = csr_src[i + 1], s2 = csr_src[i + 2], s3 = csr_src[i + 3];
        u16x8 v0 = *reinterpret_cast<const u16x8*>(&hs[(size_t)s0 * C + q * 8]);
        u16x8 v1 = *reinterpret_cast<const u16x8*>(&hs[(size_t)s1 * C + q * 8]);
        u16x8 v2 = *reinterpret_cast<const u16x8*>(&hs[(size_t)s2 * C + q * 8]);
        u16x8 v3 = *reinterpret_cast<const u16x8*>(&hs[(size_t)s3 * C + q * 8]);
        #pragma unroll
        for (int j = 0; j < 8; ++j)
            acc[j] += (bf2f(v0[j]) + bf2f(v1[j])) + (bf2f(v2[j]) + bf2f(v3[j]));
    }
    for (; i < end; ++i) {
        int s0 = csr_src[i];
        u16x8 v0 = *reinterpret_cast<const u16x8*>(&hs[(size_t)s0 * C + q * 8]);
        #pragma unroll
        for (int j = 0; j < 8; ++j) acc[j] += bf2f(v0[j]);
    }

    float w = dinv[node];
    float4 b0 = reinterpret_cast<const float4*>(b)[q * 2];
    float4 b1 = reinterpret_cast<const float4*>(b)[q * 2 + 1];
    float bb[8] = {b0.x, b0.y, b0.z, b0.w, b1.x, b1.y, b1.z, b1.w};
    u16x8 o;
    #pragma unroll
    for (int j = 0; j < 8; ++j) {
        float v = w * acc[j] + bb[j];
        if (RELU) v = fmaxf(v, 0.0f);
        o[j] = f2bf(v);
    }
    *reinterpret_cast<u16x8*>(&outp[(size_t)node * C + q * 8]) = o;
}

// ---------------- decoder ----------------

__global__ __launch_bounds__(256) void k_decode(const int* __restrict__ esrc,
                                                const int* __restrict__ edst,
                                                const unsigned short* __restrict__ z,
                                                float* __restrict__ out) {
    int tid = threadIdx.x;
    int e = blockIdx.x * 32 + tid / 8;
    int q = tid % 8;
    if (e >= N_EDGES) return;
    int s = esrc[e], d = edst[e];
    u16x8 a = *reinterpret_cast<const u16x8*>(&z[(size_t)s * OUT_CH + q * 8]);
    u16x8 b = *reinterpret_cast<const u16x8*>(&z[(size_t)d * OUT_CH + q * 8]);
    float dot = 0.0f;
    #pragma unroll
    for (int j = 0; j < 8; ++j) dot += bf2f(a[j]) * bf2f(b[j]);
    dot += __shfl_xor(dot, 1);
    dot += __shfl_xor(dot, 2);
    dot += __shfl_xor(dot, 4);
    if (q == 0) out[e] = 1.0f / (1.0f + expf(-dot));
}

// ---------------- launch ----------------

extern "C" void kernel_launch(void* const* d_in, const int* in_sizes, int n_in,
                              void* d_out, int out_size, void* d_ws, size_t ws_size,
                              hipStream_t stream) {
    const float* x  = (const float*)d_in[0];
    const int*   ei = (const int*)d_in[1];
    const float* W1 = (const float*)d_in[2];
    const float* b1 = (const float*)d_in[3];
    const float* W2 = (const float*)d_in[4];
    const float* b2 = (const float*)d_in[5];
    float* out = (float*)d_out;

    const int* src = ei;
    const int* dst = ei + N_EDGES;

    // workspace layout; overlays exploit liveness:
    //   bsorted dead after k_bucket_csr -> xb overlays it
    //   xb dead after k_gemm1 -> hs2/z overlay it
    char* ws = (char*)d_ws;
    int*   ghist   = (int*)(ws + 0x000000);       // 1 MB
    int*   goff    = (int*)(ws + 0x100000);       // 1 MB
    int*   btot    = (int*)(ws + 0x200000);       // 4 KB
    int*   bbase   = (int*)(ws + 0x202000);       // 4.1 KB
    int*   rowoff  = (int*)(ws + 0x210000);       // 400 KB
    float* dinv    = (float*)(ws + 0x290000);     // 400 KB
    unsigned short* Wf1 = (unsigned short*)(ws + 0x310000);   // 64 KB frag-linear
    unsigned short* Wf2 = (unsigned short*)(ws + 0x320000);   // 16 KB frag-linear
    int*   csr_src = (int*)(ws + 0x400000);       // 6.4 MB
    int2*  bsorted = (int2*)(ws + 0xB00000);      // 12.8 MB (dead after CSR build)
    unsigned short* xb  = (unsigned short*)(ws + 0xB00000);   // 51.2 MB (dead after gemm1)
    unsigned short* hs1 = (unsigned short*)(ws + 0x3C00000);  // 25.6 MB
    unsigned short* hs2 = (unsigned short*)(ws + 0xB00000);   // 12.8 MB (over dead xb)
    unsigned short* z   = (unsigned short*)(ws + 0x2800000);  // 12.8 MB (over dead xb tail)

    // --- CSR build (no global atomics) ---
    k_hist<<<NPART, 256, 0, stream>>>(dst, ghist);
    k_scan_cols<<<NB, 256, 0, stream>>>(ghist, goff, btot);
    k_scan_base<<<1, NB, 0, stream>>>(btot, bbase);
    k_partition<<<NPART, 256, 0, stream>>>(src, dst, goff, bbase, bsorted);
    k_bucket_csr<<<NB_USED, 256, 0, stream>>>(bsorted, bbase, rowoff, dinv, csr_src);

    // --- x cast + weight fragment layout ---
    k_cast<<<2048, 256, 0, stream>>>(x, xb);
    k_wt1<<<16, 256, 0, stream>>>(W1, Wf1);
    k_wt2<<<4, 256, 0, stream>>>(W2, Wf2);

    // --- layer 1 GEMM ---
    k_gemm1<<<NTILES, 256, 0, stream>>>(xb, Wf1, dinv, hs1);

    // --- fused: gather1 + bias/relu + GEMM2 -> hs2 ---
    k_agg_gemm2<<<NTILES, 256, 0, stream>>>(rowoff, csr_src, hs1, dinv, b1, Wf2, hs2);

    // --- layer 2 aggregation -> z ---
    k_gather_agg<OUT_CH, false><<<(N_NODES * 8 + 255) / 256, 256, 0, stream>>>(
        rowoff, csr_src, hs2, dinv, b2, z);

    // --- decoder ---
    k_decode<<<N_EDGES / 32, 256, 0, stream>>>(src, dst, z, out);
}